// Round 1
// baseline (144.873 us; speedup 1.0000x reference)
//
#include <hip/hip_runtime.h>

typedef short short8 __attribute__((ext_vector_type(8)));
typedef float f32x4 __attribute__((ext_vector_type(4)));

#define KP 288  // K = 257 padded to 9*32

// workspace layout (bytes)
#define OFF_P    0ULL         // p bf16      [16384][288]  9437184
#define OFF_CP   9437184ULL   // cp bf16     [1024][288]    589824
#define OFF_A2   10027008ULL  // a2 f32      [1024][4]       16384
#define OFF_C2   10043392ULL  // c2 f32      [1024][4]       16384
#define OFF_IX   10059776ULL  // packed idx  [1024]           4096
#define OFF_NUM  10063872ULL  // num f32     [16384]         65536
#define OFF_DEN  10129408ULL  // den f32     [16384]         65536

__device__ __forceinline__ unsigned short f2bf(float f) {
  unsigned u = __float_as_uint(f);
  return (unsigned short)((u + 0x7FFFu + ((u >> 16) & 1u)) >> 16);
}

// ---------------- prep: p features, cp->bf16, rule consts, zero num/den ----
__global__ __launch_bounds__(256) void prep_kernel(
    const float* __restrict__ x, const float* __restrict__ att,
    const float* __restrict__ pp, const float* __restrict__ th,
    const float* __restrict__ sg, const float* __restrict__ mk,
    const float* __restrict__ cp, const int* __restrict__ fidx,
    const int* __restrict__ pairs, unsigned char* __restrict__ ws)
{
  __shared__ float xa[128 * 68];
  unsigned short* p_out  = (unsigned short*)(ws + OFF_P);
  unsigned short* cp_out = (unsigned short*)(ws + OFF_CP);
  float* a2o = (float*)(ws + OFF_A2);
  float* c2o = (float*)(ws + OFF_C2);
  unsigned* ixo = (unsigned*)(ws + OFF_IX);
  int bid = blockIdx.x, t = threadIdx.x;

  if (bid < 128) {  // p features for 128 batch rows
    int b0 = bid * 128;
    float4 a4 = ((const float4*)att)[t & 15];
#pragma unroll
    for (int pass = 0; pass < 8; ++pass) {
      int row = pass * 16 + (t >> 4);
      float4 v = ((const float4*)(x + (size_t)(b0 + row) * 64))[t & 15];
      v.x *= a4.x; v.y *= a4.y; v.z *= a4.z; v.w *= a4.w;
      *(float4*)&xa[row * 68 + (t & 15) * 4] = v;
    }
    __syncthreads();
    int row = t >> 1, h = t & 1;
    const float* xr = &xa[row * 68];
    unsigned short* po = p_out + (size_t)(b0 + row) * KP;
    for (int k = 0; k < 144; ++k) {
      int i = 2 * k + h;
      float v;
      if (i < 64) v = xr[i];
      else if (i < 128) { float u = xr[i - 64]; v = u * u; }
      else if (i < 256) { int pi = i - 128; v = xr[pairs[2 * pi]] * xr[pairs[2 * pi + 1]]; }
      else if (i == 256) v = 1.f;
      else v = 0.f;
      po[i] = f2bf(v);
    }
  } else if (bid < 416) {  // cp -> bf16 padded
    int e = (bid - 128) * 1024 + t * 4;
#pragma unroll
    for (int q = 0; q < 4; ++q, ++e) {
      int r = e / KP, c = e - r * KP;
      cp_out[e] = f2bf(c < 257 ? cp[r * 257 + c] : 0.f);
    }
  } else if (bid < 420) {  // rule constants: z2 = a2*sel + c2; masked literal -> factor 1
    int r = (bid - 416) * 256 + t;
    float p = pp[r];
    unsigned pk = 0;
#pragma unroll
    for (int l = 0; l < 4; ++l) {
      float m = mk[r * 4 + l], s = sg[r * 4 + l], tt = th[r * 4 + l];
      float A, C;
      if (m != 0.f) { A = -1.44269504f * p * s; C = 1.44269504f * p * s * tt; }
      else          { A = 0.f;                  C = -126.f; }  // exp2(-126) ~ 0 -> factor 1
      a2o[r * 4 + l] = A; c2o[r * 4 + l] = C;
      pk |= ((unsigned)fidx[r * 4 + l] & 0xFFu) << (8 * l);
    }
    ixo[r] = pk;
  } else {  // zero num/den (ws is poisoned 0xAA before every call)
    float* dst = (float*)(ws + (bid == 420 ? OFF_NUM : OFF_DEN));
#pragma unroll
    for (int q = 0; q < 64; ++q) dst[q * 256 + t] = 0.f;
  }
}

// ---------------- main: bf16 MFMA GEMM (o = p . cp^T) fused with firing ----
__global__ __launch_bounds__(256) void main_kernel(
    const unsigned char* __restrict__ ws,
    const float* __restrict__ x, const float* __restrict__ att,
    float* __restrict__ numg, float* __restrict__ deng)
{
  __shared__ float xa[128 * 68];   // x_att tile, stride 68 to spread gather banks
  __shared__ short lA[128 * 32];   // p tile   [row][k], 16B-block XOR swizzle
  __shared__ short lB[128 * 32];   // cp tile  [rule][k]
  const unsigned short* P  = (const unsigned short*)(ws + OFF_P);
  const unsigned short* CP = (const unsigned short*)(ws + OFF_CP);
  const float4* A2p = (const float4*)(ws + OFF_A2);
  const float4* C2p = (const float4*)(ws + OFF_C2);
  const unsigned* IX = (const unsigned*)(ws + OFF_IX);

  int t = threadIdx.x, l = t & 63, w = t >> 6;
  int g = l >> 4, lr = l & 15;
  int b0 = blockIdx.x * 128, r0 = blockIdx.y * 128;
  int wr = (w >> 1) * 64, wc = (w & 1) * 64;  // 2x2 waves, 64x64 wave tile

  {  // stage x_att tile (coalesced)
    float4 a4 = ((const float4*)att)[t & 15];
#pragma unroll
    for (int pass = 0; pass < 8; ++pass) {
      int row = pass * 16 + (t >> 4);
      float4 v = ((const float4*)(x + (size_t)(b0 + row) * 64))[t & 15];
      v.x *= a4.x; v.y *= a4.y; v.z *= a4.z; v.w *= a4.w;
      *(float4*)&xa[row * 68 + (t & 15) * 4] = v;
    }
  }

  f32x4 acc[4][4];
#pragma unroll
  for (int mi = 0; mi < 4; ++mi)
#pragma unroll
    for (int ni = 0; ni < 4; ++ni)
      acc[mi][ni] = (f32x4){0.f, 0.f, 0.f, 0.f};

  int rsub = t >> 2, blk = t & 3;
  for (int ks = 0; ks < 9; ++ks) {
    int k0 = ks * 32;
#pragma unroll
    for (int c = 0; c < 2; ++c) {  // reg-staged LDS fill, swizzled store
      int row = c * 64 + rsub;
      int s = (row ^ (row >> 2)) & 3;
      short8 va = *(const short8*)(P  + (size_t)(b0 + row) * KP + k0 + blk * 8);
      short8 vb = *(const short8*)(CP + (size_t)(r0 + row) * KP + k0 + blk * 8);
      *(short8*)&lA[row * 32 + ((blk ^ s) * 8)] = va;
      *(short8*)&lB[row * 32 + ((blk ^ s) * 8)] = vb;
    }
    __syncthreads();
    short8 aF[4], bF[4];
#pragma unroll
    for (int mi = 0; mi < 4; ++mi) {
      int row = wr + mi * 16 + lr;
      int s = (row ^ (row >> 2)) & 3;
      aF[mi] = *(const short8*)&lA[row * 32 + ((g ^ s) * 8)];
    }
#pragma unroll
    for (int ni = 0; ni < 4; ++ni) {
      int row = wc + ni * 16 + lr;
      int s = (row ^ (row >> 2)) & 3;
      bF[ni] = *(const short8*)&lB[row * 32 + ((g ^ s) * 8)];
    }
#pragma unroll
    for (int mi = 0; mi < 4; ++mi)
#pragma unroll
      for (int ni = 0; ni < 4; ++ni)
        acc[mi][ni] = __builtin_amdgcn_mfma_f32_16x16x32_bf16(aF[mi], bF[ni], acc[mi][ni], 0, 0, 0);
    __syncthreads();
  }

  // ---- fused firing epilogue: firing = rcp(prod_l (1 + exp2(a2*sel + c2)))
  float num[4][4], den[4][4];
#pragma unroll
  for (int mi = 0; mi < 4; ++mi)
#pragma unroll
    for (int j = 0; j < 4; ++j) { num[mi][j] = 0.f; den[mi][j] = 0.f; }

#pragma unroll
  for (int ni = 0; ni < 4; ++ni) {
    int rule = r0 + wc + ni * 16 + lr;      // C layout: col = lane&15
    unsigned pk = IX[rule];
    float4 A2 = A2p[rule], C2 = C2p[rule];
    int f0 = pk & 255, f1 = (pk >> 8) & 255, f2 = (pk >> 16) & 255, f3 = (pk >> 24) & 255;
#pragma unroll
    for (int mi = 0; mi < 4; ++mi) {
      int rb = wr + mi * 16 + (g << 2);     // C layout: row = (lane>>4)*4 + reg
#pragma unroll
      for (int j = 0; j < 4; ++j) {
        const float* xr = &xa[(rb + j) * 68];
        float D = 1.f;
        float e0 = exp2f(fmaf(A2.x, xr[f0], C2.x)); D = fmaf(D, e0, D);
        float e1 = exp2f(fmaf(A2.y, xr[f1], C2.y)); D = fmaf(D, e1, D);
        float e2 = exp2f(fmaf(A2.z, xr[f2], C2.z)); D = fmaf(D, e2, D);
        float e3 = exp2f(fmaf(A2.w, xr[f3], C2.w)); D = fmaf(D, e3, D);
        float fir = __builtin_amdgcn_rcpf(D);
        num[mi][j] = fmaf(fir, acc[mi][ni][j], num[mi][j]);
        den[mi][j] += fir;
      }
    }
  }

  // reduce across the 16 lanes holding different rule columns
#pragma unroll
  for (int mi = 0; mi < 4; ++mi)
#pragma unroll
    for (int j = 0; j < 4; ++j) {
      float n = num[mi][j], d = den[mi][j];
#pragma unroll
      for (int off = 1; off < 16; off <<= 1) {
        n += __shfl_xor(n, off, 64);
        d += __shfl_xor(d, off, 64);
      }
      num[mi][j] = n; den[mi][j] = d;
    }

  // lane lr commits value (mi,j) = (lr>>2, lr&3) — static selection, no scratch
  float nv = 0.f, dv = 0.f;
#pragma unroll
  for (int mi = 0; mi < 4; ++mi)
#pragma unroll
    for (int j = 0; j < 4; ++j)
      if (lr == mi * 4 + j) { nv = num[mi][j]; dv = den[mi][j]; }

  int rowg = b0 + wr + (lr >> 2) * 16 + (g << 2) + (lr & 3);
  atomicAdd(&numg[rowg], nv);
  atomicAdd(&deng[rowg], dv);
}

// ---------------- finalize ----------------
__global__ __launch_bounds__(256) void fin_kernel(
    const float* __restrict__ numg, const float* __restrict__ deng,
    float* __restrict__ y)
{
  int i = blockIdx.x * 256 + threadIdx.x;
  y[i] = numg[i] / (deng[i] + 1e-8f);
}

extern "C" void kernel_launch(void* const* d_in, const int* in_sizes, int n_in,
                              void* d_out, int out_size, void* d_ws, size_t ws_size,
                              hipStream_t stream) {
  (void)in_sizes; (void)n_in; (void)out_size; (void)ws_size;
  const float* x    = (const float*)d_in[0];
  const float* att  = (const float*)d_in[1];
  const float* pp   = (const float*)d_in[2];
  const float* th   = (const float*)d_in[3];
  const float* sg   = (const float*)d_in[4];
  const float* mk   = (const float*)d_in[5];
  const float* cp   = (const float*)d_in[6];
  const int* fidx   = (const int*)d_in[7];
  const int* pairs  = (const int*)d_in[8];
  unsigned char* ws = (unsigned char*)d_ws;
  float* numg = (float*)(ws + OFF_NUM);
  float* deng = (float*)(ws + OFF_DEN);

  prep_kernel<<<422, 256, 0, stream>>>(x, att, pp, th, sg, mk, cp, fidx, pairs, ws);
  main_kernel<<<dim3(128, 8), 256, 0, stream>>>(ws, x, att, numg, deng);
  fin_kernel<<<64, 256, 0, stream>>>(numg, deng, (float*)d_out);
}

// Round 2
// 118.898 us; speedup vs baseline: 1.2185x; 1.2185x over previous
//
#include <hip/hip_runtime.h>

typedef short short8 __attribute__((ext_vector_type(8)));
typedef float f32x4 __attribute__((ext_vector_type(4)));

#define KP 288  // K = 257 padded to 9*32

// workspace layout (bytes)
#define OFF_CP   0ULL        // cp bf16 [1024][288]   589824
#define OFF_A2   589824ULL   // a2 f32  [1024][4]      16384
#define OFF_C2   606208ULL   // c2 f32  [1024][4]      16384
#define OFF_IX   622592ULL   // packed fidx u32 [1024]  4096
#define OFF_PAIR 626688ULL   // packed pairs u16 [128]   256
#define OFF_NUM  626944ULL   // num f32 [16384]        65536
#define OFF_DEN  692480ULL   // den f32 [16384]        65536

__device__ __forceinline__ unsigned short f2bf(float f) {
  unsigned u = __float_as_uint(f);
  return (unsigned short)((u + 0x7FFFu + ((u >> 16) & 1u)) >> 16);
}

// ---------------- prep: cp->bf16, rule consts, pair pack, zero num/den ----
__global__ __launch_bounds__(256) void prep_kernel(
    const float* __restrict__ pp, const float* __restrict__ th,
    const float* __restrict__ sg, const float* __restrict__ mk,
    const float* __restrict__ cp, const int* __restrict__ fidx,
    const int* __restrict__ pairs, unsigned char* __restrict__ ws)
{
  unsigned short* cp_out = (unsigned short*)(ws + OFF_CP);
  float* a2o = (float*)(ws + OFF_A2);
  float* c2o = (float*)(ws + OFF_C2);
  unsigned* ixo = (unsigned*)(ws + OFF_IX);
  unsigned short* pro = (unsigned short*)(ws + OFF_PAIR);
  int bid = blockIdx.x, t = threadIdx.x;

  if (bid < 288) {  // cp -> bf16, zero-padded to 288 cols
    int e = bid * 1024 + t * 4;
#pragma unroll
    for (int q = 0; q < 4; ++q, ++e) {
      int r = e / KP, c = e - r * KP;
      cp_out[e] = f2bf(c < 257 ? cp[r * 257 + c] : 0.f);
    }
  } else if (bid < 292) {  // rule consts: factor = 1/(1+exp2(A*sel+C)); masked -> 1
    int r = (bid - 288) * 256 + t;
    float p = pp[r];
    unsigned pk = 0;
#pragma unroll
    for (int l = 0; l < 4; ++l) {
      float m = mk[r * 4 + l], s = sg[r * 4 + l], tt = th[r * 4 + l];
      float A, C;
      if (m != 0.f) { A = -1.44269504f * p * s; C = 1.44269504f * p * s * tt; }
      else          { A = 0.f;                  C = -126.f; }  // exp2(-126) ~ 0 -> factor 1
      a2o[r * 4 + l] = A; c2o[r * 4 + l] = C;
      pk |= ((unsigned)fidx[r * 4 + l] & 0xFFu) << (8 * l);
    }
    ixo[r] = pk;
  } else if (bid == 292) {  // pack interaction pairs: lo byte f0, hi byte f1
    if (t < 128)
      pro[t] = (unsigned short)((pairs[2 * t] & 0xFF) | ((pairs[2 * t + 1] & 0xFF) << 8));
  } else {  // zero num/den (ws is re-poisoned 0xAA before every call)
    float* dst = (float*)(ws + (bid == 293 ? OFF_NUM : OFF_DEN));
#pragma unroll
    for (int q = 0; q < 64; ++q) dst[q * 256 + t] = 0.f;
  }
}

// ---------------- main: C[rule][batch] = cp . p^T, fused firing + on-the-fly p
// grid (256 b-blocks x 4 r-blocks); block = 256 rules x 64 batches; 4 blocks/CU.
__global__ __launch_bounds__(256, 4) void main_kernel(
    const unsigned char* __restrict__ ws,
    const float* __restrict__ x, const float* __restrict__ att,
    float* __restrict__ numg, float* __restrict__ deng)
{
  __shared__ float xa[64 * 68];           // 17408 B, stride 68 -> gather 2-way max
  __shared__ short lCP[256 * 32];         // 16384 B, 16B-block XOR swizzle
  __shared__ short lP[64 * 32];           //  4096 B, same swizzle
  __shared__ unsigned short lPair[128];   //   256 B

  const unsigned short* CP = (const unsigned short*)(ws + OFF_CP);
  const float4* A2p = (const float4*)(ws + OFF_A2);
  const float4* C2p = (const float4*)(ws + OFF_C2);
  const unsigned* IX = (const unsigned*)(ws + OFF_IX);
  const unsigned short* PRW = (const unsigned short*)(ws + OFF_PAIR);

  int t = threadIdx.x, l = t & 63, w = t >> 6;
  int g = l >> 4, lr = l & 15;
  int b0 = blockIdx.x * 64, r0 = blockIdx.y * 256;

  if (t < 128) lPair[t] = PRW[t];
  {  // stage x_att tile (64 rows x 64 f32), coalesced float4
#pragma unroll
    for (int i = 0; i < 4; ++i) {
      int idx = t + i * 256, row = idx >> 4, c4 = idx & 15;
      float4 a4 = ((const float4*)att)[c4];
      float4 v = ((const float4*)(x + (size_t)(b0 + row) * 64))[c4];
      v.x *= a4.x; v.y *= a4.y; v.z *= a4.z; v.w *= a4.w;
      *(float4*)&xa[row * 68 + c4 * 4] = v;
    }
  }
  __syncthreads();  // xa + lPair ready

  f32x4 acc[4][4];
#pragma unroll
  for (int mi = 0; mi < 4; ++mi)
#pragma unroll
    for (int ni = 0; ni < 4; ++ni)
      acc[mi][ni] = (f32x4){0.f, 0.f, 0.f, 0.f};

  int row2 = t >> 2, q = t & 3;                 // staging ids: 64 rows x 4 col-blocks
  int sw2 = (row2 ^ (row2 >> 2)) & 3;
  const float* xr2 = &xa[row2 * 68];

#pragma unroll
  for (int ks = 0; ks < 9; ++ks) {
    int k0 = ks * 32;
    // -- load cp sub-tiles to regs (consumed after barrier; latency overlaps p-gen)
    short8 cpr[4];
#pragma unroll
    for (int i = 0; i < 4; ++i) {
      int rowc = row2 + i * 64;
      cpr[i] = *(const short8*)(CP + (size_t)(r0 + rowc) * KP + k0 + q * 8);
    }
    // -- generate p feature block fb..fb+7 for batch row row2 (region is
    //    uniform per ks since all boundaries are multiples of 32)
    short8 vp;
    int fb = k0 + q * 8;
    if (fb < 64) {
      float4 u0 = *(const float4*)&xr2[fb], u1 = *(const float4*)&xr2[fb + 4];
      vp[0] = f2bf(u0.x); vp[1] = f2bf(u0.y); vp[2] = f2bf(u0.z); vp[3] = f2bf(u0.w);
      vp[4] = f2bf(u1.x); vp[5] = f2bf(u1.y); vp[6] = f2bf(u1.z); vp[7] = f2bf(u1.w);
    } else if (fb < 128) {
      float4 u0 = *(const float4*)&xr2[fb - 64], u1 = *(const float4*)&xr2[fb - 60];
      vp[0] = f2bf(u0.x * u0.x); vp[1] = f2bf(u0.y * u0.y);
      vp[2] = f2bf(u0.z * u0.z); vp[3] = f2bf(u0.w * u0.w);
      vp[4] = f2bf(u1.x * u1.x); vp[5] = f2bf(u1.y * u1.y);
      vp[6] = f2bf(u1.z * u1.z); vp[7] = f2bf(u1.w * u1.w);
    } else if (fb < 256) {
      const unsigned* pw = (const unsigned*)&lPair[fb - 128];
#pragma unroll
      for (int u = 0; u < 4; ++u) {
        unsigned pk = pw[u];
        vp[2 * u]     = f2bf(xr2[pk & 255] * xr2[(pk >> 8) & 255]);
        vp[2 * u + 1] = f2bf(xr2[(pk >> 16) & 255] * xr2[pk >> 24]);
      }
    } else {
#pragma unroll
      for (int j = 0; j < 8; ++j) vp[j] = (fb + j == 256) ? (short)0x3F80 : (short)0;
    }
    __syncthreads();  // prior iter's frag reads complete
#pragma unroll
    for (int i = 0; i < 4; ++i) {
      int rowc = row2 + i * 64;
      int swc = (rowc ^ (rowc >> 2)) & 3;
      *(short8*)&lCP[rowc * 32 + ((q ^ swc) * 8)] = cpr[i];
    }
    *(short8*)&lP[row2 * 32 + ((q ^ sw2) * 8)] = vp;
    __syncthreads();
    // -- fragments (XOR-swizzled reads, 2-way max) + MFMA
    short8 aF[4], bF[4];
#pragma unroll
    for (int mi = 0; mi < 4; ++mi) {
      int row = w * 64 + mi * 16 + lr;
      int s = (row ^ (row >> 2)) & 3;
      aF[mi] = *(const short8*)&lCP[row * 32 + ((g ^ s) * 8)];
    }
#pragma unroll
    for (int ni = 0; ni < 4; ++ni) {
      int row = ni * 16 + lr;
      int s = (row ^ (row >> 2)) & 3;
      bF[ni] = *(const short8*)&lP[row * 32 + ((g ^ s) * 8)];
    }
#pragma unroll
    for (int mi = 0; mi < 4; ++mi)
#pragma unroll
      for (int ni = 0; ni < 4; ++ni)
        acc[mi][ni] = __builtin_amdgcn_mfma_f32_16x16x32_bf16(aF[mi], bF[ni], acc[mi][ni], 0, 0, 0);
  }

  // ---- fused firing epilogue. C layout: row = rule = w*64+mi*16+g*4+j (g-uniform
  // per 16 lanes -> const loads broadcast), col = batch = ni*16+lr (gathers 2-way free).
  float num[4] = {0.f, 0.f, 0.f, 0.f}, den[4] = {0.f, 0.f, 0.f, 0.f};
#pragma unroll
  for (int mi = 0; mi < 4; ++mi) {
#pragma unroll
    for (int j = 0; j < 4; ++j) {
      int rule = r0 + w * 64 + mi * 16 + (g << 2) + j;
      float4 A2 = A2p[rule], C2 = C2p[rule];
      unsigned pk = IX[rule];
      int f0 = pk & 255, f1 = (pk >> 8) & 255, f2 = (pk >> 16) & 255, f3 = pk >> 24;
#pragma unroll
      for (int ni = 0; ni < 4; ++ni) {
        const float* xr = &xa[(ni * 16 + lr) * 68];
        float D = 1.f;
        float e0 = exp2f(fmaf(A2.x, xr[f0], C2.x)); D = fmaf(D, e0, D);
        float e1 = exp2f(fmaf(A2.y, xr[f1], C2.y)); D = fmaf(D, e1, D);
        float e2 = exp2f(fmaf(A2.z, xr[f2], C2.z)); D = fmaf(D, e2, D);
        float e3 = exp2f(fmaf(A2.w, xr[f3], C2.w)); D = fmaf(D, e3, D);
        float fir = __builtin_amdgcn_rcpf(D);
        num[ni] = fmaf(fir, acc[mi][ni][j], num[ni]);
        den[ni] += fir;
      }
    }
  }

  // reduce over the 4 lane-groups (g) which hold different rules of same batch col
#pragma unroll
  for (int ni = 0; ni < 4; ++ni) {
    float n = num[ni], d = den[ni];
    n += __shfl_xor(n, 16, 64); n += __shfl_xor(n, 32, 64);
    d += __shfl_xor(d, 16, 64); d += __shfl_xor(d, 32, 64);
    num[ni] = n; den[ni] = d;
  }
  float nv = 0.f, dv = 0.f;
#pragma unroll
  for (int ni = 0; ni < 4; ++ni)
    if (g == ni) { nv = num[ni]; dv = den[ni]; }
  atomicAdd(&numg[b0 + (g << 4) + lr], nv);
  atomicAdd(&deng[b0 + (g << 4) + lr], dv);
}

// ---------------- finalize ----------------
__global__ __launch_bounds__(256) void fin_kernel(
    const float* __restrict__ numg, const float* __restrict__ deng,
    float* __restrict__ y)
{
  int i = blockIdx.x * 256 + threadIdx.x;
  y[i] = numg[i] / (deng[i] + 1e-8f);
}

extern "C" void kernel_launch(void* const* d_in, const int* in_sizes, int n_in,
                              void* d_out, int out_size, void* d_ws, size_t ws_size,
                              hipStream_t stream) {
  (void)in_sizes; (void)n_in; (void)out_size; (void)ws_size;
  const float* x    = (const float*)d_in[0];
  const float* att  = (const float*)d_in[1];
  const float* pp   = (const float*)d_in[2];
  const float* th   = (const float*)d_in[3];
  const float* sg   = (const float*)d_in[4];
  const float* mk   = (const float*)d_in[5];
  const float* cp   = (const float*)d_in[6];
  const int* fidx   = (const int*)d_in[7];
  const int* pairs  = (const int*)d_in[8];
  unsigned char* ws = (unsigned char*)d_ws;
  float* numg = (float*)(ws + OFF_NUM);
  float* deng = (float*)(ws + OFF_DEN);

  prep_kernel<<<295, 256, 0, stream>>>(pp, th, sg, mk, cp, fidx, pairs, ws);
  main_kernel<<<dim3(256, 4), 256, 0, stream>>>(ws, x, att, numg, deng);
  fin_kernel<<<64, 256, 0, stream>>>(numg, deng, (float*)d_out);
}

// Round 3
// 104.494 us; speedup vs baseline: 1.3864x; 1.1378x over previous
//
#include <hip/hip_runtime.h>

typedef short short8 __attribute__((ext_vector_type(8)));
typedef float f32x4 __attribute__((ext_vector_type(4)));

#define KP 288  // K = 257 padded to 9*32

// workspace layout (bytes)
#define OFF_CP   0ULL        // cp bf16 [1024][288]   589824
#define OFF_A2   589824ULL   // a2 f32  [1024][4]      16384
#define OFF_C2   606208ULL   // c2 f32  [1024][4]      16384
#define OFF_IX   622592ULL   // packed fidx u32 [1024]  4096
#define OFF_PAIR 626688ULL   // packed pairs u16 [128]   256
#define OFF_NUM  626944ULL   // num f32 [16384]        65536
#define OFF_DEN  692480ULL   // den f32 [16384]        65536

#define XS 65  // xa LDS stride: bank = (row + f) % 32 -> gathers ~2-way (free)

__device__ __forceinline__ unsigned short f2bf(float f) {
  unsigned u = __float_as_uint(f);
  return (unsigned short)((u + 0x7FFFu + ((u >> 16) & 1u)) >> 16);
}

// ---------------- prep: cp->bf16, rule consts, pair pack, zero num/den ----
__global__ __launch_bounds__(256) void prep_kernel(
    const float* __restrict__ pp, const float* __restrict__ th,
    const float* __restrict__ sg, const float* __restrict__ mk,
    const float* __restrict__ cp, const int* __restrict__ fidx,
    const int* __restrict__ pairs, unsigned char* __restrict__ ws)
{
  unsigned short* cp_out = (unsigned short*)(ws + OFF_CP);
  float* a2o = (float*)(ws + OFF_A2);
  float* c2o = (float*)(ws + OFF_C2);
  unsigned* ixo = (unsigned*)(ws + OFF_IX);
  unsigned short* pro = (unsigned short*)(ws + OFF_PAIR);
  int bid = blockIdx.x, t = threadIdx.x;

  if (bid < 288) {  // cp -> bf16, zero-padded to 288 cols
    int e = bid * 1024 + t * 4;
#pragma unroll
    for (int q = 0; q < 4; ++q, ++e) {
      int r = e / KP, c = e - r * KP;
      cp_out[e] = f2bf(c < 257 ? cp[r * 257 + c] : 0.f);
    }
  } else if (bid < 292) {  // rule consts: factor = 1/(1+exp2(A*sel+C)); masked -> 1
    int r = (bid - 288) * 256 + t;
    float p = pp[r];
    unsigned pk = 0;
#pragma unroll
    for (int l = 0; l < 4; ++l) {
      float m = mk[r * 4 + l], s = sg[r * 4 + l], tt = th[r * 4 + l];
      float A, C;
      if (m != 0.f) { A = -1.44269504f * p * s; C = 1.44269504f * p * s * tt; }
      else          { A = 0.f;                  C = -126.f; }  // exp2(-126) ~ 0 -> factor 1
      a2o[r * 4 + l] = A; c2o[r * 4 + l] = C;
      pk |= ((unsigned)fidx[r * 4 + l] & 0xFFu) << (8 * l);
    }
    ixo[r] = pk;
  } else if (bid == 292) {  // pack interaction pairs: lo byte f0, hi byte f1
    if (t < 128)
      pro[t] = (unsigned short)((pairs[2 * t] & 0xFF) | ((pairs[2 * t + 1] & 0xFF) << 8));
  } else {  // zero num/den (ws is re-poisoned 0xAA before every call)
    float* dst = (float*)(ws + (bid == 293 ? OFF_NUM : OFF_DEN));
#pragma unroll
    for (int q = 0; q < 64; ++q) dst[q * 256 + t] = 0.f;
  }
}

// ---------------- main: C[rule][batch] = cp . p^T, fused firing + on-the-fly p
// grid (256 b-blocks x 4 r-blocks); block = 256 rules x 64 batches.
// launch_bounds (256,3): VGPR cap 170 — R2's (256,4)=128 cap caused 63 MB of
// scratch spill (WRITE_SIZE counter). LDS 37.4 KB -> 3 blocks/CU.
__global__ __launch_bounds__(256, 3) void main_kernel(
    const unsigned char* __restrict__ ws,
    const float* __restrict__ x, const float* __restrict__ att,
    float* __restrict__ numg, float* __restrict__ deng)
{
  __shared__ float xa[64 * XS];           // 16640 B
  __shared__ short lCP[256 * 32];         // 16384 B, 16B-block XOR swizzle
  __shared__ short lP[64 * 32];           //  4096 B, same swizzle
  __shared__ unsigned short lPair[128];   //   256 B

  const unsigned short* CP = (const unsigned short*)(ws + OFF_CP);
  const float4* A2p = (const float4*)(ws + OFF_A2);
  const float4* C2p = (const float4*)(ws + OFF_C2);
  const unsigned* IX = (const unsigned*)(ws + OFF_IX);
  const unsigned short* PRW = (const unsigned short*)(ws + OFF_PAIR);

  int t = threadIdx.x, l = t & 63, w = t >> 6;
  int g = l >> 4, lr = l & 15;
  int b0 = blockIdx.x * 64, r0 = blockIdx.y * 256;

  if (t < 128) lPair[t] = PRW[t];
  {  // stage x_att tile (64 rows x 64 f32); scalar stores (stride-65, 2-way banks)
#pragma unroll
    for (int i = 0; i < 4; ++i) {
      int idx = t + i * 256, row = idx >> 4, c4 = idx & 15;
      float4 a4 = ((const float4*)att)[c4];
      float4 v = ((const float4*)(x + (size_t)(b0 + row) * 64))[c4];
      float* dst = &xa[row * XS + c4 * 4];
      dst[0] = v.x * a4.x; dst[1] = v.y * a4.y;
      dst[2] = v.z * a4.z; dst[3] = v.w * a4.w;
    }
  }
  __syncthreads();  // xa + lPair ready

  f32x4 acc[4][4];
#pragma unroll
  for (int mi = 0; mi < 4; ++mi)
#pragma unroll
    for (int ni = 0; ni < 4; ++ni)
      acc[mi][ni] = (f32x4){0.f, 0.f, 0.f, 0.f};

  int row2 = t >> 2, q = t & 3;                 // staging ids: 64 rows x 4 col-blocks
  int sw2 = (row2 ^ (row2 >> 2)) & 3;
  const float* xr2 = &xa[row2 * XS];

  // 1-deep cpr prefetch; loop kept rolled to bound register liveness
  short8 cpr[4];
#pragma unroll
  for (int i = 0; i < 4; ++i)
    cpr[i] = *(const short8*)(CP + (size_t)(r0 + row2 + i * 64) * KP + q * 8);

  for (int ks = 0; ks < 9; ++ks) {
    int k0 = ks * 32;
    int fb = k0 + q * 8;
    // -- generate p feature block fb..fb+7 for batch row row2 (branch on ks:
    //    wave-uniform scalar branches; regions are 32-aligned)
    short8 vp;
    if (ks < 2) {                 // raw x_att
#pragma unroll
      for (int j = 0; j < 8; ++j) vp[j] = f2bf(xr2[fb + j]);
    } else if (ks < 4) {          // squares
#pragma unroll
      for (int j = 0; j < 8; ++j) { float u = xr2[fb - 64 + j]; vp[j] = f2bf(u * u); }
    } else if (ks < 8) {          // interaction pairs
      const unsigned* pw = (const unsigned*)&lPair[fb - 128];
#pragma unroll
      for (int u = 0; u < 4; ++u) {
        unsigned pk = pw[u];
        vp[2 * u]     = f2bf(xr2[pk & 255] * xr2[(pk >> 8) & 255]);
        vp[2 * u + 1] = f2bf(xr2[(pk >> 16) & 255] * xr2[pk >> 24]);
      }
    } else {                      // ones column + zero pad
#pragma unroll
      for (int j = 0; j < 8; ++j) vp[j] = (fb + j == 256) ? (short)0x3F80 : (short)0;
    }
    __syncthreads();  // prior iter's frag reads complete
#pragma unroll
    for (int i = 0; i < 4; ++i) {
      int rowc = row2 + i * 64;
      int swc = (rowc ^ (rowc >> 2)) & 3;
      *(short8*)&lCP[rowc * 32 + ((q ^ swc) * 8)] = cpr[i];
    }
    *(short8*)&lP[row2 * 32 + ((q ^ sw2) * 8)] = vp;
    if (ks < 8) {  // issue next cpr loads; latency hides under frag+MFMA phase
#pragma unroll
      for (int i = 0; i < 4; ++i)
        cpr[i] = *(const short8*)(CP + (size_t)(r0 + row2 + i * 64) * KP + k0 + 32 + q * 8);
    }
    __syncthreads();
    // -- fragments (XOR-swizzled reads, 2-way max): bF first, aF per-mi to cut liveness
    short8 bF[4];
#pragma unroll
    for (int ni = 0; ni < 4; ++ni) {
      int row = ni * 16 + lr;
      int s = (row ^ (row >> 2)) & 3;
      bF[ni] = *(const short8*)&lP[row * 32 + ((g ^ s) * 8)];
    }
#pragma unroll
    for (int mi = 0; mi < 4; ++mi) {
      int row = w * 64 + mi * 16 + lr;
      int s = (row ^ (row >> 2)) & 3;
      short8 aF = *(const short8*)&lCP[row * 32 + ((g ^ s) * 8)];
#pragma unroll
      for (int ni = 0; ni < 4; ++ni)
        acc[mi][ni] = __builtin_amdgcn_mfma_f32_16x16x32_bf16(aF, bF[ni], acc[mi][ni], 0, 0, 0);
    }
  }

  // ---- fused firing epilogue. C layout: row = rule = w*64+mi*16+g*4+j (g-uniform
  // per 16 lanes), col = batch = ni*16+lr. Gather bank = (16ni+lr+f)%32: ~2-way.
  float num[4] = {0.f, 0.f, 0.f, 0.f}, den[4] = {0.f, 0.f, 0.f, 0.f};
#pragma unroll
  for (int mi = 0; mi < 4; ++mi) {
#pragma unroll
    for (int j = 0; j < 4; ++j) {
      int rule = r0 + w * 64 + mi * 16 + (g << 2) + j;
      float4 A2 = A2p[rule], C2 = C2p[rule];
      unsigned pk = IX[rule];
      int f0 = pk & 255, f1 = (pk >> 8) & 255, f2 = (pk >> 16) & 255, f3 = pk >> 24;
#pragma unroll
      for (int ni = 0; ni < 4; ++ni) {
        const float* xr = &xa[(ni * 16 + lr) * XS];
        float D = 1.f;
        float e0 = exp2f(fmaf(A2.x, xr[f0], C2.x)); D = fmaf(D, e0, D);
        float e1 = exp2f(fmaf(A2.y, xr[f1], C2.y)); D = fmaf(D, e1, D);
        float e2 = exp2f(fmaf(A2.z, xr[f2], C2.z)); D = fmaf(D, e2, D);
        float e3 = exp2f(fmaf(A2.w, xr[f3], C2.w)); D = fmaf(D, e3, D);
        float fir = __builtin_amdgcn_rcpf(D);
        num[ni] = fmaf(fir, acc[mi][ni][j], num[ni]);
        den[ni] += fir;
      }
    }
  }

  // reduce over the 4 lane-groups (g) which hold different rules of same batch col
#pragma unroll
  for (int ni = 0; ni < 4; ++ni) {
    float n = num[ni], d = den[ni];
    n += __shfl_xor(n, 16, 64); n += __shfl_xor(n, 32, 64);
    d += __shfl_xor(d, 16, 64); d += __shfl_xor(d, 32, 64);
    num[ni] = n; den[ni] = d;
  }
  float nv = 0.f, dv = 0.f;
#pragma unroll
  for (int ni = 0; ni < 4; ++ni)
    if (g == ni) { nv = num[ni]; dv = den[ni]; }
  atomicAdd(&numg[b0 + (g << 4) + lr], nv);
  atomicAdd(&deng[b0 + (g << 4) + lr], dv);
}

// ---------------- finalize ----------------
__global__ __launch_bounds__(256) void fin_kernel(
    const float* __restrict__ numg, const float* __restrict__ deng,
    float* __restrict__ y)
{
  int i = blockIdx.x * 256 + threadIdx.x;
  y[i] = numg[i] / (deng[i] + 1e-8f);
}

extern "C" void kernel_launch(void* const* d_in, const int* in_sizes, int n_in,
                              void* d_out, int out_size, void* d_ws, size_t ws_size,
                              hipStream_t stream) {
  (void)in_sizes; (void)n_in; (void)out_size; (void)ws_size;
  const float* x    = (const float*)d_in[0];
  const float* att  = (const float*)d_in[1];
  const float* pp   = (const float*)d_in[2];
  const float* th   = (const float*)d_in[3];
  const float* sg   = (const float*)d_in[4];
  const float* mk   = (const float*)d_in[5];
  const float* cp   = (const float*)d_in[6];
  const int* fidx   = (const int*)d_in[7];
  const int* pairs  = (const int*)d_in[8];
  unsigned char* ws = (unsigned char*)d_ws;
  float* numg = (float*)(ws + OFF_NUM);
  float* deng = (float*)(ws + OFF_DEN);

  prep_kernel<<<295, 256, 0, stream>>>(pp, th, sg, mk, cp, fidx, pairs, ws);
  main_kernel<<<dim3(256, 4), 256, 0, stream>>>(ws, x, att, numg, deng);
  fin_kernel<<<64, 256, 0, stream>>>(numg, deng, (float*)d_out);
}